// Round 3
// baseline (110.435 us; speedup 1.0000x reference)
//
#include <hip/hip_runtime.h>
#include <cfloat>

// ECE: N=1e6 rows, C=100 fp32 logits, int32 labels, 15 bins.
// K1: contiguous per-block row range; 4 lanes/row (6 float4 + 1 float each),
//     argmax via shfl; wave-uniform fast path (all bins==14) -> shuffle
//     reduce + 3 LDS atomics/wave; partials -> ws[s*G + block].
// K2: single 1024-thread block: coalesced reduce of ws + finalize -> d_out.

#define ECE_NBINS 15
#define ECE_NSTATS 45   // count[15], sum_acc[15], sum_conf[15]

__global__ __launch_bounds__(256) void ece_partial_kernel(
    const float* __restrict__ logits, const int* __restrict__ labels,
    float* __restrict__ ws, int n_rows, int G)
{
    __shared__ float s_stats[ECE_NSTATS];
    const int tid = threadIdx.x;
    if (tid < ECE_NSTATS) s_stats[tid] = 0.0f;
    __syncthreads();

    const int sub  = tid & 3;   // lane within 4-lane row group
    const int lrow = tid >> 2;  // 0..63 local row
    const int lane = tid & 63;

    // contiguous row partition: block b owns [r0, r0+cnt)
    const int base = n_rows / G;
    const int rem  = n_rows % G;
    const int b    = blockIdx.x;
    const int r0   = b * base + (b < rem ? b : rem);
    const int cnt  = base + (b < rem ? 1 : 0);
    const int nt   = (cnt + 63) / 64;

    for (int t = 0; t < nt; ++t) {
        const int lr = t * 64 + lrow;          // local row in this block
        const bool valid = lr < cnt;
        const int r = r0 + lr;

        float best = -FLT_MAX;
        int   bidx = 0;
        float accv = 0.0f;
        int   bin  = 14;

        if (valid) {
            const float*  rowf = logits + (size_t)r * 100;
            const float4* rowp = (const float4*)rowf;
            // lane `sub` reads float4 j = sub+4k (k=0..5) + scalar elem 96+sub.
            #pragma unroll
            for (int k = 0; k < 6; ++k) {
                const float4 v = rowp[sub + 4 * k];
                const int e = (sub + 4 * k) * 4;
                if (v.x > best) { best = v.x; bidx = e;     }
                if (v.y > best) { best = v.y; bidx = e + 1; }
                if (v.z > best) { best = v.z; bidx = e + 2; }
                if (v.w > best) { best = v.w; bidx = e + 3; }
            }
            const float vl = rowf[96 + sub];
            if (vl > best) { best = vl; bidx = 96 + sub; }
            // combine across the 4 lanes of this row; tie -> lower index
            #pragma unroll
            for (int m = 1; m <= 2; m <<= 1) {
                const float ov = __shfl_xor(best, m);
                const int   oi = __shfl_xor(bidx, m);
                if (ov > best || (ov == best && oi < bidx)) { best = ov; bidx = oi; }
            }
            if (sub == 0) accv = (bidx == labels[r]) ? 1.0f : 0.0f;
            bin = (int)ceilf(best * 15.0f) - 1;   // lower < c <= upper
            bin = bin < 0 ? 0 : (bin > 14 ? 14 : bin);
        }

        // per-row contribution carried by sub==0 lane only
        const bool own = valid && (sub == 0);
        float c1 = own ? 1.0f : 0.0f;
        float ca = own ? accv : 0.0f;
        float cc = own ? best : 0.0f;

        if (__all(!valid || bin == 14)) {
            // fast path (~98%): whole wave in bin 14 -> shuffle reduce
            #pragma unroll
            for (int m = 32; m >= 1; m >>= 1) {
                c1 += __shfl_xor(c1, m);
                ca += __shfl_xor(ca, m);
                cc += __shfl_xor(cc, m);
            }
            if (lane == 0 && c1 > 0.0f) {
                atomicAdd(&s_stats[14], c1);
                atomicAdd(&s_stats[29], ca);
                atomicAdd(&s_stats[44], cc);
            }
        } else if (own) {
            atomicAdd(&s_stats[bin],      1.0f);
            atomicAdd(&s_stats[15 + bin], ca);
            atomicAdd(&s_stats[30 + bin], cc);
        }
    }
    __syncthreads();
    if (tid < ECE_NSTATS) ws[(size_t)tid * G + blockIdx.x] = s_stats[tid];
}

// One 1024-thread block: reduce ws[45][G] and finalize -> out[0..1].
__global__ __launch_bounds__(1024) void ece_final_kernel(
    const float* __restrict__ ws, float* __restrict__ out, int G, float n_total)
{
    __shared__ float s_sum[ECE_NSTATS];
    const int tid  = threadIdx.x;
    const int wave = tid >> 6;   // 0..15
    const int lane = tid & 63;

    for (int s = wave; s < ECE_NSTATS; s += 16) {
        float v = 0.0f;
        const float* p = ws + (size_t)s * G;
        for (int j = lane; j < G; j += 64) v += p[j];
        #pragma unroll
        for (int m = 32; m >= 1; m >>= 1) v += __shfl_xor(v, m);
        if (lane == 0) s_sum[s] = v;
    }
    __syncthreads();

    if (tid < 64) {
        float ece = 0.0f, acc = 0.0f;
        if (tid < ECE_NBINS) {
            const float c = s_sum[tid];
            if (c > 0.0f) {
                const float prop = c / n_total;
                const float a = s_sum[15 + tid] / c;
                const float f = s_sum[30 + tid] / c;
                ece = fabsf(f - a) * prop;
                acc = a * prop;
            }
        }
        #pragma unroll
        for (int m = 32; m >= 1; m >>= 1) {
            ece += __shfl_xor(ece, m);
            acc += __shfl_xor(acc, m);
        }
        if (tid == 0) {
            out[0] = ece * 100.0f;
            out[1] = acc * 100.0f;
        }
    }
}

extern "C" void kernel_launch(void* const* d_in, const int* in_sizes, int n_in,
                              void* d_out, int out_size, void* d_ws, size_t ws_size,
                              hipStream_t stream) {
    const float* logits = (const float*)d_in[0];
    const int*   labels = (const int*)d_in[1];
    float*       out    = (float*)d_out;
    float*       ws     = (float*)d_ws;

    const int n_rows = in_sizes[1];              // N = 1,000,000 (labels count)

    int G = 2048;                                 // 8 blocks/CU on 256 CUs
    const size_t maxG = ws_size / (ECE_NSTATS * sizeof(float));
    if ((size_t)G > maxG) G = (int)maxG;
    if (G > (n_rows + 63) / 64) G = (n_rows + 63) / 64;
    if (G < 1) G = 1;

    ece_partial_kernel<<<G, 256, 0, stream>>>(logits, labels, ws, n_rows, G);
    ece_final_kernel<<<1, 1024, 0, stream>>>((const float*)ws, out, G, (float)n_rows);
}